// Round 4
// baseline (736.051 us; speedup 1.0000x reference)
//
#include <hip/hip_runtime.h>
#include <math.h>

#define NQ 100000
#define NL 32
#define QD 384
#define LD 1024
#define H 128
#define E_TOT 1000000
#define E_SEE 750000
#define E_PRED 250000
#define NN (NQ + NL)          // 100032
#define EPS 1e-5f

#define NB_SCAN ((NN + 255) / 256)    // 391
#define NB_G64 (NN / 64)              // 1563 (exact)
#define NB_X64 ((NQ + 63) / 64)       // 1563

typedef __attribute__((ext_vector_type(8))) short short8;
typedef __attribute__((ext_vector_type(4))) short short4v;
typedef __attribute__((ext_vector_type(4))) float f32x4;

__device__ __forceinline__ unsigned short f2bf(float f) {
  unsigned int u = __builtin_bit_cast(unsigned int, f);
  u = (u + 0x7FFFu + ((u >> 16) & 1u)) >> 16;
  return (unsigned short)u;
}

// ---------------- CSR build ----------------

__global__ void k_ew_hist(const int* __restrict__ ecs, const int* __restrict__ EI,
                          const float* __restrict__ ewt, const float* __restrict__ Wem,
                          const float* __restrict__ bem, float* __restrict__ ew,
                          int* __restrict__ cnt, int2* __restrict__ se) {
  int e = blockIdx.x * 256 + threadIdx.x;
  if (e >= E_SEE) return;
  int idx = ecs[e];
  int s = EI[idx];
  int d = EI[E_TOT + idx];
  se[e] = make_int2(s, d);           // linearize for k_fill
  atomicAdd(&cnt[d], 1);
  float w = ewt[idx] * Wem[0] + bem[0];
  ew[e] = w > 0.f ? w : 0.01f * w;
}

__global__ void k_scan_block(const int* __restrict__ cnt, int* __restrict__ bsum) {
  __shared__ int red[256];
  int i = blockIdx.x * 256 + threadIdx.x;
  red[threadIdx.x] = (i < NN) ? cnt[i] : 0;
  __syncthreads();
  for (int s = 128; s > 0; s >>= 1) {
    if (threadIdx.x < s) red[threadIdx.x] += red[threadIdx.x + s];
    __syncthreads();
  }
  if (threadIdx.x == 0) bsum[blockIdx.x] = red[0];
}

__global__ void k_scan_top(const int* __restrict__ bsum, int* __restrict__ boff) {
  __shared__ int buf[2][512];
  int t = threadIdx.x;
  int v = (t < NB_SCAN) ? bsum[t] : 0;
  buf[0][t] = v;
  __syncthreads();
  int src = 0;
  for (int d = 1; d < 512; d <<= 1) {
    int x = buf[src][t];
    if (t >= d) x += buf[src][t - d];
    buf[src ^ 1][t] = x;
    __syncthreads();
    src ^= 1;
  }
  if (t < NB_SCAN) boff[t] = buf[src][t] - v;  // exclusive
}

__global__ void k_scan_write(const int* __restrict__ cnt, const int* __restrict__ boff,
                             int* __restrict__ off) {
  __shared__ int buf[2][256];
  int t = threadIdx.x;
  int i = blockIdx.x * 256 + t;
  int v = (i < NN) ? cnt[i] : 0;
  buf[0][t] = v;
  __syncthreads();
  int src = 0;
  for (int d = 1; d < 256; d <<= 1) {
    int x = buf[src][t];
    if (t >= d) x += buf[src][t - d];
    buf[src ^ 1][t] = x;
    __syncthreads();
    src ^= 1;
  }
  if (i < NN) off[i] = boff[blockIdx.x] + buf[src][t] - v;
  if (i == 0) off[NN] = E_SEE;
}

__global__ void k_fill(const int2* __restrict__ se, const float* __restrict__ ew,
                       const int* __restrict__ off, int* __restrict__ cur,
                       int* __restrict__ csr_src, float* __restrict__ csr_ew) {
  int e = blockIdx.x * 256 + threadIdx.x;
  if (e >= E_SEE) return;
  int2 sd = se[e];
  int p = off[sd.y] + atomicAdd(&cur[sd.y], 1);
  csr_src[p] = sd.x;
  csr_ew[p] = ew[e];
}

// ---------------- prep: bf16 transposed weights [n][k] ----------------

__global__ void k_prep(const float* __restrict__ Wq, const float* __restrict__ W1m,
                       const float* __restrict__ W2m,
                       unsigned short* __restrict__ Wqt, unsigned short* __restrict__ W1t,
                       unsigned short* __restrict__ W2t) {
  int i = blockIdx.x * 256 + threadIdx.x;  // grid covers 81920
  const int tot1 = QD * H;                 // 49152
  const int tot2 = H * H;                  // 16384
  if (i < tot1) {
    int n = i / QD, k = i - n * QD;
    Wqt[i] = f2bf(Wq[(size_t)k * H + n]);
  } else if (i < tot1 + tot2) {
    int j = i - tot1;
    int n = j >> 7, k = j & 127;
    W1t[j] = f2bf(W1m[(size_t)k * H + n]);
  } else if (i < tot1 + 2 * tot2) {
    int j = i - tot1 - tot2;
    int n = j >> 7, k = j & 127;
    W2t[j] = f2bf(W2m[(size_t)k * H + n]);
  }
}

// ---------------- llm rows: split-K partial + combine ----------------

__global__ __launch_bounds__(128) void k_llm_part(const float* __restrict__ lf,
                                                  const float* __restrict__ Wl,
                                                  float* __restrict__ part) {
  int r = blockIdx.x >> 3;   // 0..31
  int s = blockIdx.x & 7;    // 0..7
  int t = threadIdx.x;       // col 0..127
  int k0 = s * 128;
  float acc = 0.f;
#pragma unroll 4
  for (int k = 0; k < 128; k += 4) {
    float a0 = lf[(size_t)r * LD + k0 + k + 0];
    float a1 = lf[(size_t)r * LD + k0 + k + 1];
    float a2 = lf[(size_t)r * LD + k0 + k + 2];
    float a3 = lf[(size_t)r * LD + k0 + k + 3];
    acc = fmaf(a0, Wl[(size_t)(k0 + k + 0) * H + t], acc);
    acc = fmaf(a1, Wl[(size_t)(k0 + k + 1) * H + t], acc);
    acc = fmaf(a2, Wl[(size_t)(k0 + k + 2) * H + t], acc);
    acc = fmaf(a3, Wl[(size_t)(k0 + k + 3) * H + t], acc);
  }
  part[(size_t)blockIdx.x * 128 + t] = acc;
}

__global__ void k_llm_comb(const float* __restrict__ part, const float* __restrict__ bl,
                           float* __restrict__ XINI) {
  int i = blockIdx.x * 256 + threadIdx.x;
  if (i >= NL * H) return;
  int r = i >> 7, t = i & 127;
  float a = bl[t];
#pragma unroll
  for (int s = 0; s < 8; s++) a += part[(size_t)(r * 8 + s) * 128 + t];
  XINI[(size_t)(NQ + r) * H + t] = a;
}

// ---------------- x_ini q rows: bf16 MFMA, 64x128 tile, K=384 ---------------
// Swapped operands: A=weights (M=cols), B=x-rows (N=rows) -> lane's 4 acc regs
// are 4 consecutive output cols -> float4 global stores.

__global__ __launch_bounds__(256) void k_xini(
    const float* __restrict__ qf, const unsigned short* __restrict__ Wqt,
    const float* __restrict__ bq, float* __restrict__ XINI) {
  __shared__ unsigned short sA[64][40];   // x rows [row][k]
  __shared__ unsigned short sB[128][40];  // weight cols [n][k]
  int tid = threadIdx.x;
  int w = tid >> 6, lane = tid & 63;
  int l15 = lane & 15, quad = lane >> 4;
  int wn = (w >> 1) * 32;   // row-half
  int wm = (w & 1) * 64;    // col-half
  int rowbase = blockIdx.x * 64;
  f32x4 acc[2][4];
#pragma unroll
  for (int i = 0; i < 2; i++)
#pragma unroll
    for (int j = 0; j < 4; j++) acc[i][j] = (f32x4){0.f, 0.f, 0.f, 0.f};

  int arow = tid >> 3, akc = (tid & 7) * 4;   // A: 32 rows/pass x 32k
  int bn = tid >> 2, bk8 = (tid & 3) * 8;     // B: 64 n/pass x 32k
  float4 pa[2];
  int4 pb[2];
#pragma unroll
  for (int p = 0; p < 2; ++p) {
    int gr = rowbase + p * 32 + arow;
    pa[p] = (gr < NQ) ? *(const float4*)&qf[(size_t)gr * QD + akc]
                      : make_float4(0.f, 0.f, 0.f, 0.f);
  }
#pragma unroll
  for (int p = 0; p < 2; ++p)
    pb[p] = *(const int4*)&Wqt[(size_t)(p * 64 + bn) * QD + bk8];

  for (int step = 0; step < 12; ++step) {
#pragma unroll
    for (int p = 0; p < 2; ++p) {
      short4v b;
      b.x = (short)f2bf(pa[p].x); b.y = (short)f2bf(pa[p].y);
      b.z = (short)f2bf(pa[p].z); b.w = (short)f2bf(pa[p].w);
      *(short4v*)&sA[p * 32 + arow][akc] = b;
    }
#pragma unroll
    for (int p = 0; p < 2; ++p) *(int4*)&sB[p * 64 + bn][bk8] = pb[p];
    __syncthreads();
    if (step + 1 < 12) {
      int kn = (step + 1) * 32;
#pragma unroll
      for (int p = 0; p < 2; ++p) {
        int gr = rowbase + p * 32 + arow;
        pa[p] = (gr < NQ) ? *(const float4*)&qf[(size_t)gr * QD + kn + akc]
                          : make_float4(0.f, 0.f, 0.f, 0.f);
      }
#pragma unroll
      for (int p = 0; p < 2; ++p)
        pb[p] = *(const int4*)&Wqt[(size_t)(p * 64 + bn) * QD + kn + bk8];
    }
    short8 af[4], bfr[2];
#pragma unroll
    for (int mt = 0; mt < 4; ++mt)
      af[mt] = *(const short8*)&sB[wm + mt * 16 + l15][quad * 8];
#pragma unroll
    for (int nt = 0; nt < 2; ++nt)
      bfr[nt] = *(const short8*)&sA[wn + nt * 16 + l15][quad * 8];
#pragma unroll
    for (int nt = 0; nt < 2; ++nt)
#pragma unroll
      for (int mt = 0; mt < 4; ++mt)
        acc[nt][mt] = __builtin_amdgcn_mfma_f32_16x16x32_bf16(
            af[mt], bfr[nt], acc[nt][mt], 0, 0, 0);
    __syncthreads();
  }
  // D[m=col: quad*4+reg][n=row: l15] -> float4 store per (nt,mt)
#pragma unroll
  for (int nt = 0; nt < 2; ++nt) {
    int row = rowbase + wn + nt * 16 + l15;
    if (row < NQ) {
#pragma unroll
      for (int mt = 0; mt < 4; ++mt) {
        int cb = wm + mt * 16 + quad * 4;
        float4 bias = *(const float4*)&bq[cb];
        float4 o = make_float4(acc[nt][mt][0] + bias.x, acc[nt][mt][1] + bias.y,
                               acc[nt][mt][2] + bias.z, acc[nt][mt][3] + bias.w);
        *(float4*)&XINI[(size_t)row * H + cb] = o;
      }
    }
  }
}

// ---------------- segment sum (one wave per node), S stored bf16 ----------------

template <bool TRANS>
__global__ __launch_bounds__(256) void k_seg(
    const float* __restrict__ Xin, const int* __restrict__ off,
    const int* __restrict__ csr_src, const float* __restrict__ csr_ew,
    const float* __restrict__ scale, const float* __restrict__ shift,
    unsigned short* __restrict__ S16, float* __restrict__ swsum,
    float* __restrict__ degf) {
  int w = blockIdx.x * 4 + (threadIdx.x >> 6);
  if (w >= NN) return;
  int lane = threadIdx.x & 63;
  int o0 = off[w], o1 = off[w + 1];
  float ax = 1.f, ay = 1.f, bx = 0.f, by = 0.f;
  if (TRANS) {
    float2 sc = *(const float2*)&scale[lane * 2];
    float2 sh = *(const float2*)&shift[lane * 2];
    ax = sc.x; ay = sc.y; bx = sh.x; by = sh.y;
  }
  float accx = 0.f, accy = 0.f, ews = 0.f;
  for (int k = o0; k < o1; ++k) {
    int s = csr_src[k];
    float2 v = *(const float2*)&Xin[(size_t)s * H + lane * 2];
    if (TRANS) {
      float t0 = fmaf(ax, v.x, bx); v.x = t0 > 0.f ? t0 : 0.01f * t0;
      float t1 = fmaf(ay, v.y, by); v.y = t1 > 0.f ? t1 : 0.01f * t1;
    }
    accx += v.x; accy += v.y;
    ews += csr_ew[k];
  }
  unsigned int pk = ((unsigned int)f2bf(accy) << 16) | f2bf(accx);
  *(unsigned int*)&S16[(size_t)w * H + lane * 2] = pk;
  if (lane == 0) { swsum[w] = ews; degf[w] = (float)(o1 - o0); }
}

// ---------------- node GEMM (bf16 MFMA, 64-tile) + residual + BN partials ----

template <bool TRANS>
__global__ __launch_bounds__(256) void k_gemm(
    const unsigned short* __restrict__ S16, const float* __restrict__ Xin,
    float* __restrict__ Xout, const unsigned short* __restrict__ Wt,
    const float* __restrict__ bm, const float* __restrict__ be,
    const float* __restrict__ We,
    const float* __restrict__ scale, const float* __restrict__ shift,
    const float* __restrict__ swsum, const float* __restrict__ degf,
    float* __restrict__ partials) {
  __shared__ unsigned short sA[64][40];
  __shared__ unsigned short sB[128][40];
  __shared__ float st[2][2][128];
  int tid = threadIdx.x;
  int w = tid >> 6, lane = tid & 63;
  int l15 = lane & 15, quad = lane >> 4;
  int wn = (w >> 1) * 32, wm = (w & 1) * 64;
  int rowbase = blockIdx.x * 64;   // NN = 1563*64 exactly: no bounds checks
  f32x4 acc[2][4];
#pragma unroll
  for (int i = 0; i < 2; i++)
#pragma unroll
    for (int j = 0; j < 4; j++) acc[i][j] = (f32x4){0.f, 0.f, 0.f, 0.f};

  int arow = tid >> 2, ak8 = (tid & 3) * 8;   // A: 64 rows x 32k, 1 int4/thread
  int bn = tid >> 2, bk8 = (tid & 3) * 8;     // B: 64 n/pass x 32k
  int4 pa;
  int4 pb[2];
  pa = *(const int4*)&S16[(size_t)(rowbase + arow) * H + ak8];
#pragma unroll
  for (int p = 0; p < 2; ++p)
    pb[p] = *(const int4*)&Wt[(size_t)(p * 64 + bn) * H + bk8];

  for (int step = 0; step < 4; ++step) {
    *(int4*)&sA[arow][ak8] = pa;
#pragma unroll
    for (int p = 0; p < 2; ++p) *(int4*)&sB[p * 64 + bn][bk8] = pb[p];
    __syncthreads();
    if (step + 1 < 4) {
      int kn = (step + 1) * 32;
      pa = *(const int4*)&S16[(size_t)(rowbase + arow) * H + kn + ak8];
#pragma unroll
      for (int p = 0; p < 2; ++p)
        pb[p] = *(const int4*)&Wt[(size_t)(p * 64 + bn) * H + kn + bk8];
    }
    short8 af[4], bfr[2];
#pragma unroll
    for (int mt = 0; mt < 4; ++mt)
      af[mt] = *(const short8*)&sB[wm + mt * 16 + l15][quad * 8];
#pragma unroll
    for (int nt = 0; nt < 2; ++nt)
      bfr[nt] = *(const short8*)&sA[wn + nt * 16 + l15][quad * 8];
#pragma unroll
    for (int nt = 0; nt < 2; ++nt)
#pragma unroll
      for (int mt = 0; mt < 4; ++mt)
        acc[nt][mt] = __builtin_amdgcn_mfma_f32_16x16x32_bf16(
            af[mt], bfr[nt], acc[nt][mt], 0, 0, 0);
    __syncthreads();
  }
  // epilogue: rows n = rowbase+wn+nt*16+l15; cols cb = wm+mt*16+quad*4 (+0..3)
  int n0 = rowbase + wn + l15;
  float dg0 = degf[n0], sw0 = swsum[n0];
  float dg1 = degf[n0 + 16], sw1 = swsum[n0 + 16];
#pragma unroll
  for (int mt = 0; mt < 4; ++mt) {
    int cb = wm + mt * 16 + quad * 4;
    float4 m4 = *(const float4*)&bm[cb];
    float4 e4 = *(const float4*)&be[cb];
    float4 cb4 = make_float4(m4.x + e4.x, m4.y + e4.y, m4.z + e4.z, m4.w + e4.w);
    float4 we4 = *(const float4*)&We[cb];
    float4 sc4, sh4;
    if (TRANS) { sc4 = *(const float4*)&scale[cb]; sh4 = *(const float4*)&shift[cb]; }
    f32x4 psum = {0.f, 0.f, 0.f, 0.f}, psq = {0.f, 0.f, 0.f, 0.f};
#pragma unroll
    for (int nt = 0; nt < 2; ++nt) {
      int n = n0 + nt * 16;
      float dg = nt ? dg1 : dg0, sw = nt ? sw1 : sw0;
      float4 rr = *(const float4*)&Xin[(size_t)n * H + cb];
      if (TRANS) {
        float t;
        t = fmaf(sc4.x, rr.x, sh4.x); rr.x = t > 0.f ? t : 0.01f * t;
        t = fmaf(sc4.y, rr.y, sh4.y); rr.y = t > 0.f ? t : 0.01f * t;
        t = fmaf(sc4.z, rr.z, sh4.z); rr.z = t > 0.f ? t : 0.01f * t;
        t = fmaf(sc4.w, rr.w, sh4.w); rr.w = t > 0.f ? t : 0.01f * t;
      }
      float4 o;
      o.x = acc[nt][mt][0] + dg * cb4.x + sw * we4.x + rr.x;
      o.y = acc[nt][mt][1] + dg * cb4.y + sw * we4.y + rr.y;
      o.z = acc[nt][mt][2] + dg * cb4.z + sw * we4.z + rr.z;
      o.w = acc[nt][mt][3] + dg * cb4.w + sw * we4.w + rr.w;
      *(float4*)&Xout[(size_t)n * H + cb] = o;
      psum[0] += o.x; psum[1] += o.y; psum[2] += o.z; psum[3] += o.w;
      psq[0] += o.x * o.x; psq[1] += o.y * o.y; psq[2] += o.z * o.z; psq[3] += o.w * o.w;
    }
    // reduce across l15 (stays within quad: masks < 16)
#pragma unroll
    for (int s = 1; s < 16; s <<= 1) {
#pragma unroll
      for (int j = 0; j < 4; ++j) {
        psum[j] += __shfl_xor(psum[j], s, 64);
        psq[j] += __shfl_xor(psq[j], s, 64);
      }
    }
    if (l15 == 0) {
      *(f32x4*)&st[0][w >> 1][cb] = psum;
      *(f32x4*)&st[1][w >> 1][cb] = psq;
    }
  }
  __syncthreads();
  int stat = tid >> 7, col = tid & 127;
  partials[(size_t)blockIdx.x * 256 + tid] = st[stat][0][col] + st[stat][1][col];
}

// ---------------- BN stats finish: one block per column ----------------

__global__ __launch_bounds__(256) void k_bnstats(
    const float* __restrict__ partials, const float* __restrict__ g,
    const float* __restrict__ beta, float* __restrict__ scale,
    float* __restrict__ shift) {
  __shared__ float rs[256], rq[256];
  int j = blockIdx.x;  // column
  int t = threadIdx.x;
  float as = 0.f, aq = 0.f;
  for (int b = t; b < NB_G64; b += 256) {
    as += partials[(size_t)b * 256 + j];
    aq += partials[(size_t)b * 256 + 128 + j];
  }
  rs[t] = as; rq[t] = aq;
  __syncthreads();
  for (int s = 128; s > 0; s >>= 1) {
    if (t < s) { rs[t] += rs[t + s]; rq[t] += rq[t + s]; }
    __syncthreads();
  }
  if (t == 0) {
    float mean = rs[0] / (float)NN;
    float var = rq[0] / (float)NN - mean * mean;
    float a = g[j] * rsqrtf(var + EPS);
    scale[j] = a;
    shift[j] = beta[j] - mean * a;
  }
}

// ---------------- edge predict (one wave per edge) ----------------

__global__ __launch_bounds__(256) void k_pred(
    const int* __restrict__ emask, const int* __restrict__ EI,
    const float* __restrict__ XINI, const float* __restrict__ X,
    const float* __restrict__ scale, const float* __restrict__ shift,
    float* __restrict__ out) {
  int i = blockIdx.x * 4 + (threadIdx.x >> 6);
  if (i >= E_PRED) return;
  int lane = threadIdx.x & 63;
  int m = emask[i];
  int p0 = EI[m];
  int p1 = EI[E_TOT + m];
  float2 a = *(const float2*)&XINI[(size_t)p0 * H + lane * 2];
  float2 b = *(const float2*)&X[(size_t)p1 * H + lane * 2];
  float2 sc = *(const float2*)&scale[lane * 2];
  float2 sh = *(const float2*)&shift[lane * 2];
  float v = a.x * fmaf(sc.x, b.x, sh.x) + a.y * fmaf(sc.y, b.y, sh.y);
#pragma unroll
  for (int mm = 32; mm > 0; mm >>= 1) v += __shfl_xor(v, mm, 64);
  if (lane == 0) out[i] = 1.f / (1.f + expf(-v * (1.f / 128.f)));
}

// ---------------- launcher ----------------

extern "C" void kernel_launch(void* const* d_in, const int* in_sizes, int n_in,
                              void* d_out, int out_size, void* d_ws, size_t ws_size,
                              hipStream_t stream) {
  const float* qf    = (const float*)d_in[0];
  const float* lf    = (const float*)d_in[1];
  const int*   EI    = (const int*)d_in[2];
  const int*   emask = (const int*)d_in[3];
  const int*   ecs   = (const int*)d_in[4];
  const float* ewt   = (const float*)d_in[5];
  const float* Wq    = (const float*)d_in[6];
  const float* bq    = (const float*)d_in[7];
  const float* Wl    = (const float*)d_in[8];
  const float* bl    = (const float*)d_in[9];
  const float* Wem   = (const float*)d_in[10];
  const float* bem   = (const float*)d_in[11];
  const float* W1m   = (const float*)d_in[12];
  const float* b1m   = (const float*)d_in[13];
  const float* W1e   = (const float*)d_in[14];
  const float* b1e   = (const float*)d_in[15];
  const float* W2m   = (const float*)d_in[16];
  const float* b2m   = (const float*)d_in[17];
  const float* W2e   = (const float*)d_in[18];
  const float* b2e   = (const float*)d_in[19];
  const float* g1    = (const float*)d_in[20];
  const float* beta1 = (const float*)d_in[21];
  const float* g2    = (const float*)d_in[22];
  const float* beta2 = (const float*)d_in[23];
  float* out = (float*)d_out;

  char* p = (char*)d_ws;
  auto alloc = [&](size_t bytes) -> void* {
    void* r = (void*)p;
    p += (bytes + 255) & ~(size_t)255;
    return r;
  };
  float* XINI    = (float*)alloc((size_t)NN * H * 4);
  float* X       = (float*)alloc((size_t)NN * H * 4);
  unsigned short* S16 = (unsigned short*)alloc((size_t)NN * H * 2);
  float* ew      = (float*)alloc((size_t)E_SEE * 4);
  float* csr_ew  = (float*)alloc((size_t)E_SEE * 4);
  int*   csr_src = (int*)alloc((size_t)E_SEE * 4);
  int2*  se      = (int2*)alloc((size_t)E_SEE * 8);
  int*   cnt     = (int*)alloc((size_t)NN * 4);
  int*   off     = (int*)alloc((size_t)(NN + 1) * 4);
  int*   cur     = (int*)alloc((size_t)NN * 4);
  int*   bsum    = (int*)alloc((size_t)NB_SCAN * 4);
  int*   boff    = (int*)alloc((size_t)NB_SCAN * 4);
  float* swsum   = (float*)alloc((size_t)NN * 4);
  float* degf    = (float*)alloc((size_t)NN * 4);
  float* partials= (float*)alloc((size_t)NB_G64 * 256 * 4);
  float* scale1  = (float*)alloc(128 * 4);
  float* shift1  = (float*)alloc(128 * 4);
  float* scale2  = (float*)alloc(128 * 4);
  float* shift2  = (float*)alloc(128 * 4);
  unsigned short* Wqt = (unsigned short*)alloc((size_t)QD * H * 2);
  unsigned short* W1t = (unsigned short*)alloc((size_t)H * H * 2);
  unsigned short* W2t = (unsigned short*)alloc((size_t)H * H * 2);
  float* llmpart = (float*)alloc((size_t)NL * 8 * H * 4);

  hipMemsetAsync(cnt, 0, (size_t)NN * 4, stream);
  hipMemsetAsync(cur, 0, (size_t)NN * 4, stream);

  int ebl = (E_SEE + 255) / 256;
  k_prep<<<320, 256, 0, stream>>>(Wq, W1m, W2m, Wqt, W1t, W2t);
  k_ew_hist<<<ebl, 256, 0, stream>>>(ecs, EI, ewt, Wem, bem, ew, cnt, se);
  k_scan_block<<<NB_SCAN, 256, 0, stream>>>(cnt, bsum);
  k_scan_top<<<1, 512, 0, stream>>>(bsum, boff);
  k_scan_write<<<NB_SCAN, 256, 0, stream>>>(cnt, boff, off);
  k_fill<<<ebl, 256, 0, stream>>>(se, ew, off, cur, csr_src, csr_ew);

  k_llm_part<<<NL * 8, 128, 0, stream>>>(lf, Wl, llmpart);
  k_llm_comb<<<(NL * H + 255) / 256, 256, 0, stream>>>(llmpart, bl, XINI);
  k_xini<<<NB_X64, 256, 0, stream>>>(qf, Wqt, bq, XINI);

  int segbl = (NN + 3) / 4;
  // layer 1
  k_seg<false><<<segbl, 256, 0, stream>>>(XINI, off, csr_src, csr_ew,
                                          nullptr, nullptr, S16, swsum, degf);
  k_gemm<false><<<NB_G64, 256, 0, stream>>>(S16, XINI, X, W1t, b1m, b1e, W1e,
                                            nullptr, nullptr, swsum, degf, partials);
  k_bnstats<<<H, 256, 0, stream>>>(partials, g1, beta1, scale1, shift1);
  // layer 2 (BN1+lrelu folded into gather & residual)
  k_seg<true><<<segbl, 256, 0, stream>>>(X, off, csr_src, csr_ew,
                                         scale1, shift1, S16, swsum, degf);
  k_gemm<true><<<NB_G64, 256, 0, stream>>>(S16, X, X, W2t, b2m, b2e, W2e,
                                           scale1, shift1, swsum, degf, partials);
  k_bnstats<<<H, 256, 0, stream>>>(partials, g2, beta2, scale2, shift2);
  // predict (BN2 folded in)
  int pbl = (E_PRED + 3) / 4;
  k_pred<<<pbl, 256, 0, stream>>>(emask, EI, XINI, X, scale2, shift2, out);
}

// Round 7
// 728.710 us; speedup vs baseline: 1.0101x; 1.0101x over previous
//
#include <hip/hip_runtime.h>
#include <math.h>

#define NQ 100000
#define NL 32
#define QD 384
#define LD 1024
#define H 128
#define E_TOT 1000000
#define E_SEE 750000
#define E_PRED 250000
#define NN (NQ + NL)          // 100032
#define EPS 1e-5f

#define NB_SCAN ((NN + 255) / 256)    // 391
#define NB_G64 (NN / 64)              // 1563 (exact)
#define NB_X64 ((NQ + 63) / 64)       // 1563

typedef __attribute__((ext_vector_type(8))) short short8;
typedef __attribute__((ext_vector_type(4))) float f32x4;

__device__ __forceinline__ unsigned short f2bf(float f) {
  unsigned int u = __builtin_bit_cast(unsigned int, f);
  u = (u + 0x7FFFu + ((u >> 16) & 1u)) >> 16;
  return (unsigned short)u;
}
__device__ __forceinline__ float bflo(unsigned int u) {
  return __builtin_bit_cast(float, u << 16);
}
__device__ __forceinline__ float bfhi(unsigned int u) {
  return __builtin_bit_cast(float, u & 0xFFFF0000u);
}
__device__ __forceinline__ unsigned int pk2(float a, float b) {
  return ((unsigned int)f2bf(b) << 16) | f2bf(a);
}

// ---------------- CSR build ----------------

__global__ void k_ew_hist(const int* __restrict__ ecs, const int* __restrict__ EI,
                          const float* __restrict__ ewt, const float* __restrict__ Wem,
                          const float* __restrict__ bem, float* __restrict__ ew,
                          int* __restrict__ cnt, int2* __restrict__ se) {
  int e = blockIdx.x * 256 + threadIdx.x;
  if (e >= E_SEE) return;
  int idx = ecs[e];
  int s = EI[idx];
  int d = EI[E_TOT + idx];
  se[e] = make_int2(s, d);
  atomicAdd(&cnt[d], 1);
  float w = ewt[idx] * Wem[0] + bem[0];
  ew[e] = w > 0.f ? w : 0.01f * w;
}

__global__ void k_scan_block(const int* __restrict__ cnt, int* __restrict__ bsum) {
  __shared__ int red[256];
  int i = blockIdx.x * 256 + threadIdx.x;
  red[threadIdx.x] = (i < NN) ? cnt[i] : 0;
  __syncthreads();
  for (int s = 128; s > 0; s >>= 1) {
    if (threadIdx.x < s) red[threadIdx.x] += red[threadIdx.x + s];
    __syncthreads();
  }
  if (threadIdx.x == 0) bsum[blockIdx.x] = red[0];
}

__global__ void k_scan_top(const int* __restrict__ bsum, int* __restrict__ boff) {
  __shared__ int buf[2][512];
  int t = threadIdx.x;
  int v = (t < NB_SCAN) ? bsum[t] : 0;
  buf[0][t] = v;
  __syncthreads();
  int src = 0;
  for (int d = 1; d < 512; d <<= 1) {
    int x = buf[src][t];
    if (t >= d) x += buf[src][t - d];
    buf[src ^ 1][t] = x;
    __syncthreads();
    src ^= 1;
  }
  if (t < NB_SCAN) boff[t] = buf[src][t] - v;  // exclusive
}

__global__ void k_scan_write(const int* __restrict__ cnt, const int* __restrict__ boff,
                             int* __restrict__ off) {
  __shared__ int buf[2][256];
  int t = threadIdx.x;
  int i = blockIdx.x * 256 + t;
  int v = (i < NN) ? cnt[i] : 0;
  buf[0][t] = v;
  __syncthreads();
  int src = 0;
  for (int d = 1; d < 256; d <<= 1) {
    int x = buf[src][t];
    if (t >= d) x += buf[src][t - d];
    buf[src ^ 1][t] = x;
    __syncthreads();
    src ^= 1;
  }
  if (i < NN) off[i] = boff[blockIdx.x] + buf[src][t] - v;
  if (i == 0) off[NN] = E_SEE;
}

__global__ void k_fill(const int2* __restrict__ se, const float* __restrict__ ew,
                       const int* __restrict__ off, int* __restrict__ cur,
                       int* __restrict__ csr_src, float* __restrict__ csr_ew) {
  int e = blockIdx.x * 256 + threadIdx.x;
  if (e >= E_SEE) return;
  int2 sd = se[e];
  int p = off[sd.y] + atomicAdd(&cur[sd.y], 1);
  csr_src[p] = sd.x;
  csr_ew[p] = ew[e];
}

// ---------------- prep: bf16 transposed weights [n][k] ----------------

__global__ void k_prep(const float* __restrict__ Wq, const float* __restrict__ W1m,
                       const float* __restrict__ W2m,
                       unsigned short* __restrict__ Wqt, unsigned short* __restrict__ W1t,
                       unsigned short* __restrict__ W2t) {
  int i = blockIdx.x * 256 + threadIdx.x;  // grid covers 81920
  const int tot1 = QD * H;                 // 49152
  const int tot2 = H * H;                  // 16384
  if (i < tot1) {
    int n = i / QD, k = i - n * QD;
    Wqt[i] = f2bf(Wq[(size_t)k * H + n]);
  } else if (i < tot1 + tot2) {
    int j = i - tot1;
    int n = j >> 7, k = j & 127;
    W1t[j] = f2bf(W1m[(size_t)k * H + n]);
  } else if (i < tot1 + 2 * tot2) {
    int j = i - tot1 - tot2;
    int n = j >> 7, k = j & 127;
    W2t[j] = f2bf(W2m[(size_t)k * H + n]);
  }
}

// ---------------- llm rows: split-K partial + combine ----------------

__global__ __launch_bounds__(128) void k_llm_part(const float* __restrict__ lf,
                                                  const float* __restrict__ Wl,
                                                  float* __restrict__ part) {
  int r = blockIdx.x >> 3;
  int s = blockIdx.x & 7;
  int t = threadIdx.x;
  int k0 = s * 128;
  float acc = 0.f;
#pragma unroll 4
  for (int k = 0; k < 128; k += 4) {
    float a0 = lf[(size_t)r * LD + k0 + k + 0];
    float a1 = lf[(size_t)r * LD + k0 + k + 1];
    float a2 = lf[(size_t)r * LD + k0 + k + 2];
    float a3 = lf[(size_t)r * LD + k0 + k + 3];
    acc = fmaf(a0, Wl[(size_t)(k0 + k + 0) * H + t], acc);
    acc = fmaf(a1, Wl[(size_t)(k0 + k + 1) * H + t], acc);
    acc = fmaf(a2, Wl[(size_t)(k0 + k + 2) * H + t], acc);
    acc = fmaf(a3, Wl[(size_t)(k0 + k + 3) * H + t], acc);
  }
  part[(size_t)blockIdx.x * 128 + t] = acc;
}

__global__ void k_llm_comb(const float* __restrict__ part, const float* __restrict__ bl,
                           unsigned short* __restrict__ XINI16) {
  int i = blockIdx.x * 256 + threadIdx.x;
  if (i >= NL * H) return;
  int r = i >> 7, t = i & 127;
  float a = bl[t];
#pragma unroll
  for (int s = 0; s < 8; s++) a += part[(size_t)(r * 8 + s) * 128 + t];
  XINI16[(size_t)(NQ + r) * H + t] = f2bf(a);
}

// ---------------- x_ini q rows: LDS-free register MFMA --------------------
// Wave = 32 rows x 64 cols. A-frag = weights (L2-resident, direct 16B loads),
// B-frag = x-rows (direct 32B fp32 loads + f2bf in regs). No LDS, no barriers.

__global__ __launch_bounds__(256) void k_xini(
    const float* __restrict__ qf, const unsigned short* __restrict__ Wqt,
    const float* __restrict__ bq, unsigned short* __restrict__ XINI16) {
  int tid = threadIdx.x;
  int w = tid >> 6, lane = tid & 63;
  int l15 = lane & 15, quad = lane >> 4;
  int wn = (w >> 1) * 32;   // row-half
  int wm = (w & 1) * 64;    // col-half
  int rowbase = blockIdx.x * 64;
  int rowq = rowbase + wn + l15;   // +nt*16
  f32x4 acc[2][4];
#pragma unroll
  for (int i = 0; i < 2; i++)
#pragma unroll
    for (int j = 0; j < 4; j++) acc[i][j] = (f32x4){0.f, 0.f, 0.f, 0.f};

#pragma unroll 3
  for (int s = 0; s < 12; ++s) {
    int k0 = s * 32 + quad * 8;
    short8 af[4];
#pragma unroll
    for (int mt = 0; mt < 4; ++mt)
      af[mt] = *(const short8*)&Wqt[(size_t)(wm + mt * 16 + l15) * QD + k0];
    short8 bfr[2];
#pragma unroll
    for (int nt = 0; nt < 2; ++nt) {
      int r = rowq + nt * 16;
      float4 f0 = make_float4(0.f, 0.f, 0.f, 0.f), f1 = f0;
      if (r < NQ) {
        f0 = *(const float4*)&qf[(size_t)r * QD + k0];
        f1 = *(const float4*)&qf[(size_t)r * QD + k0 + 4];
      }
      short8 b;
      b[0] = (short)f2bf(f0.x); b[1] = (short)f2bf(f0.y);
      b[2] = (short)f2bf(f0.z); b[3] = (short)f2bf(f0.w);
      b[4] = (short)f2bf(f1.x); b[5] = (short)f2bf(f1.y);
      b[6] = (short)f2bf(f1.z); b[7] = (short)f2bf(f1.w);
      bfr[nt] = b;
    }
#pragma unroll
    for (int nt = 0; nt < 2; ++nt)
#pragma unroll
      for (int mt = 0; mt < 4; ++mt)
        acc[nt][mt] = __builtin_amdgcn_mfma_f32_16x16x32_bf16(
            af[mt], bfr[nt], acc[nt][mt], 0, 0, 0);
  }
  // D[m=col: quad*4+reg][n=row: l15]
#pragma unroll
  for (int nt = 0; nt < 2; ++nt) {
    int row = rowq + nt * 16;
    if (row < NQ) {
#pragma unroll
      for (int mt = 0; mt < 4; ++mt) {
        int cb = wm + mt * 16 + quad * 4;
        float4 bias = *(const float4*)&bq[cb];
        uint2 pk = make_uint2(pk2(acc[nt][mt][0] + bias.x, acc[nt][mt][1] + bias.y),
                              pk2(acc[nt][mt][2] + bias.z, acc[nt][mt][3] + bias.w));
        *(uint2*)&XINI16[(size_t)row * H + cb] = pk;
      }
    }
  }
}

// ---------------- segment sum (one wave per node), bf16 gather ----------------

template <bool TRANS>
__global__ __launch_bounds__(256) void k_seg(
    const unsigned short* __restrict__ X16, const int* __restrict__ off,
    const int* __restrict__ csr_src, const float* __restrict__ csr_ew,
    const float* __restrict__ scale, const float* __restrict__ shift,
    unsigned short* __restrict__ S16, float* __restrict__ swsum,
    float* __restrict__ degf) {
  int w = blockIdx.x * 4 + (threadIdx.x >> 6);
  if (w >= NN) return;
  int lane = threadIdx.x & 63;
  int o0 = off[w], o1 = off[w + 1];
  float ax = 1.f, ay = 1.f, bx = 0.f, by = 0.f;
  if (TRANS) {
    float2 sc = *(const float2*)&scale[lane * 2];
    float2 sh = *(const float2*)&shift[lane * 2];
    ax = sc.x; ay = sc.y; bx = sh.x; by = sh.y;
  }
  float accx = 0.f, accy = 0.f, ews = 0.f;
  for (int k = o0; k < o1; ++k) {
    int s = csr_src[k];
    unsigned int pk = *(const unsigned int*)&X16[(size_t)s * H + lane * 2];
    float vx = bflo(pk), vy = bfhi(pk);
    if (TRANS) {
      float t0 = fmaf(ax, vx, bx); vx = t0 > 0.f ? t0 : 0.01f * t0;
      float t1 = fmaf(ay, vy, by); vy = t1 > 0.f ? t1 : 0.01f * t1;
    }
    accx += vx; accy += vy;
    ews += csr_ew[k];
  }
  *(unsigned int*)&S16[(size_t)w * H + lane * 2] = pk2(accx, accy);
  if (lane == 0) { swsum[w] = ews; degf[w] = (float)(o1 - o0); }
}

// ---------------- node GEMM: LDS-free register MFMA + epilogue --------------
// out = S@W + deg*(bm+be) + swsum*We + resid; resid from bf16 mirror.
// BN partials computed from fp32 epilogue values (pre-rounding).

template <bool TRANS>
__global__ __launch_bounds__(256) void k_gemm(
    const unsigned short* __restrict__ S16, const unsigned short* __restrict__ Xin16,
    unsigned short* __restrict__ Xout16,
    const unsigned short* __restrict__ Wt,
    const float* __restrict__ bm, const float* __restrict__ be,
    const float* __restrict__ We,
    const float* __restrict__ scale, const float* __restrict__ shift,
    const float* __restrict__ swsum, const float* __restrict__ degf,
    float* __restrict__ partials) {
  __shared__ float st[2][2][128];
  int tid = threadIdx.x;
  int w = tid >> 6, lane = tid & 63;
  int l15 = lane & 15, quad = lane >> 4;
  int wn = (w >> 1) * 32, wm = (w & 1) * 64;
  int rowbase = blockIdx.x * 64;   // NN = 1563*64 exactly
  int rowq = rowbase + wn + l15;
  f32x4 acc[2][4];
#pragma unroll
  for (int i = 0; i < 2; i++)
#pragma unroll
    for (int j = 0; j < 4; j++) acc[i][j] = (f32x4){0.f, 0.f, 0.f, 0.f};

#pragma unroll
  for (int s = 0; s < 4; ++s) {
    int k0 = s * 32 + quad * 8;
    short8 af[4], bfr[2];
#pragma unroll
    for (int mt = 0; mt < 4; ++mt)
      af[mt] = *(const short8*)&Wt[(size_t)(wm + mt * 16 + l15) * H + k0];
#pragma unroll
    for (int nt = 0; nt < 2; ++nt)
      bfr[nt] = *(const short8*)&S16[(size_t)(rowq + nt * 16) * H + k0];
#pragma unroll
    for (int nt = 0; nt < 2; ++nt)
#pragma unroll
      for (int mt = 0; mt < 4; ++mt)
        acc[nt][mt] = __builtin_amdgcn_mfma_f32_16x16x32_bf16(
            af[mt], bfr[nt], acc[nt][mt], 0, 0, 0);
  }
  // epilogue: rows n = rowq+nt*16; cols cb = wm+mt*16+quad*4 (+0..3)
  float dg0 = degf[rowq], sw0 = swsum[rowq];
  float dg1 = degf[rowq + 16], sw1 = swsum[rowq + 16];
#pragma unroll
  for (int mt = 0; mt < 4; ++mt) {
    int cb = wm + mt * 16 + quad * 4;
    float4 m4 = *(const float4*)&bm[cb];
    float4 e4 = *(const float4*)&be[cb];
    float4 cb4 = make_float4(m4.x + e4.x, m4.y + e4.y, m4.z + e4.z, m4.w + e4.w);
    float4 we4 = *(const float4*)&We[cb];
    float4 sc4, sh4;
    if (TRANS) { sc4 = *(const float4*)&scale[cb]; sh4 = *(const float4*)&shift[cb]; }
    f32x4 psum = {0.f, 0.f, 0.f, 0.f}, psq = {0.f, 0.f, 0.f, 0.f};
#pragma unroll
    for (int nt = 0; nt < 2; ++nt) {
      int n = rowq + nt * 16;
      float dg = nt ? dg1 : dg0, sw = nt ? sw1 : sw0;
      uint2 pr = *(const uint2*)&Xin16[(size_t)n * H + cb];
      float4 rr = make_float4(bflo(pr.x), bfhi(pr.x), bflo(pr.y), bfhi(pr.y));
      if (TRANS) {
        float t;
        t = fmaf(sc4.x, rr.x, sh4.x); rr.x = t > 0.f ? t : 0.01f * t;
        t = fmaf(sc4.y, rr.y, sh4.y); rr.y = t > 0.f ? t : 0.01f * t;
        t = fmaf(sc4.z, rr.z, sh4.z); rr.z = t > 0.f ? t : 0.01f * t;
        t = fmaf(sc4.w, rr.w, sh4.w); rr.w = t > 0.f ? t : 0.01f * t;
      }
      float4 o;
      o.x = acc[nt][mt][0] + dg * cb4.x + sw * we4.x + rr.x;
      o.y = acc[nt][mt][1] + dg * cb4.y + sw * we4.y + rr.y;
      o.z = acc[nt][mt][2] + dg * cb4.z + sw * we4.z + rr.z;
      o.w = acc[nt][mt][3] + dg * cb4.w + sw * we4.w + rr.w;
      uint2 pk = make_uint2(pk2(o.x, o.y), pk2(o.z, o.w));
      *(uint2*)&Xout16[(size_t)n * H + cb] = pk;
      psum[0] += o.x; psum[1] += o.y; psum[2] += o.z; psum[3] += o.w;
      psq[0] += o.x * o.x; psq[1] += o.y * o.y; psq[2] += o.z * o.z; psq[3] += o.w * o.w;
    }
#pragma unroll
    for (int s = 1; s < 16; s <<= 1) {
#pragma unroll
      for (int j = 0; j < 4; ++j) {
        psum[j] += __shfl_xor(psum[j], s, 64);
        psq[j] += __shfl_xor(psq[j], s, 64);
      }
    }
    if (l15 == 0) {
      *(f32x4*)&st[0][w >> 1][cb] = psum;
      *(f32x4*)&st[1][w >> 1][cb] = psq;
    }
  }
  __syncthreads();
  int stat = tid >> 7, col = tid & 127;
  partials[(size_t)blockIdx.x * 256 + tid] = st[stat][0][col] + st[stat][1][col];
}

// ---------------- BN stats finish: one block per column ----------------

__global__ __launch_bounds__(256) void k_bnstats(
    const float* __restrict__ partials, const float* __restrict__ g,
    const float* __restrict__ beta, float* __restrict__ scale,
    float* __restrict__ shift) {
  __shared__ float rs[256], rq[256];
  int j = blockIdx.x;
  int t = threadIdx.x;
  float as = 0.f, aq = 0.f;
  for (int b = t; b < NB_G64; b += 256) {
    as += partials[(size_t)b * 256 + j];
    aq += partials[(size_t)b * 256 + 128 + j];
  }
  rs[t] = as; rq[t] = aq;
  __syncthreads();
  for (int s = 128; s > 0; s >>= 1) {
    if (t < s) { rs[t] += rs[t + s]; rq[t] += rq[t + s]; }
    __syncthreads();
  }
  if (t == 0) {
    float mean = rs[0] / (float)NN;
    float var = rq[0] / (float)NN - mean * mean;
    float a = g[j] * rsqrtf(var + EPS);
    scale[j] = a;
    shift[j] = beta[j] - mean * a;
  }
}

// ---------------- edge predict (one wave per edge), bf16 gathers ------------

__global__ __launch_bounds__(256) void k_pred(
    const int* __restrict__ emask, const int* __restrict__ EI,
    const unsigned short* __restrict__ XINI16, const unsigned short* __restrict__ X16,
    const float* __restrict__ scale, const float* __restrict__ shift,
    float* __restrict__ out) {
  int i = blockIdx.x * 4 + (threadIdx.x >> 6);
  if (i >= E_PRED) return;
  int lane = threadIdx.x & 63;
  int m = emask[i];
  int p0 = EI[m];
  int p1 = EI[E_TOT + m];
  unsigned int pa = *(const unsigned int*)&XINI16[(size_t)p0 * H + lane * 2];
  unsigned int pb = *(const unsigned int*)&X16[(size_t)p1 * H + lane * 2];
  float2 sc = *(const float2*)&scale[lane * 2];
  float2 sh = *(const float2*)&shift[lane * 2];
  float v = bflo(pa) * fmaf(sc.x, bflo(pb), sh.x) +
            bfhi(pa) * fmaf(sc.y, bfhi(pb), sh.y);
#pragma unroll
  for (int mm = 32; mm > 0; mm >>= 1) v += __shfl_xor(v, mm, 64);
  if (lane == 0) out[i] = 1.f / (1.f + expf(-v * (1.f / 128.f)));
}

// ---------------- launcher ----------------

extern "C" void kernel_launch(void* const* d_in, const int* in_sizes, int n_in,
                              void* d_out, int out_size, void* d_ws, size_t ws_size,
                              hipStream_t stream) {
  const float* qf    = (const float*)d_in[0];
  const float* lf    = (const float*)d_in[1];
  const int*   EI    = (const int*)d_in[2];
  const int*   emask = (const int*)d_in[3];
  const int*   ecs   = (const int*)d_in[4];
  const float* ewt   = (const float*)d_in[5];
  const float* Wq    = (const float*)d_in[6];
  const float* bq    = (const float*)d_in[7];
  const float* Wl    = (const float*)d_in[8];
  const float* bl    = (const float*)d_in[9];
  const float* Wem   = (const float*)d_in[10];
  const float* bem   = (const float*)d_in[11];
  const float* W1m   = (const float*)d_in[12];
  const float* b1m   = (const float*)d_in[13];
  const float* W1e   = (const float*)d_in[14];
  const float* b1e   = (const float*)d_in[15];
  const float* W2m   = (const float*)d_in[16];
  const float* b2m   = (const float*)d_in[17];
  const float* W2e   = (const float*)d_in[18];
  const float* b2e   = (const float*)d_in[19];
  const float* g1    = (const float*)d_in[20];
  const float* beta1 = (const float*)d_in[21];
  const float* g2    = (const float*)d_in[22];
  const float* beta2 = (const float*)d_in[23];
  float* out = (float*)d_out;

  char* p = (char*)d_ws;
  auto alloc = [&](size_t bytes) -> void* {
    void* r = (void*)p;
    p += (bytes + 255) & ~(size_t)255;
    return r;
  };
  unsigned short* XINI16 = (unsigned short*)alloc((size_t)NN * H * 2);
  unsigned short* X16    = (unsigned short*)alloc((size_t)NN * H * 2);
  unsigned short* S16    = (unsigned short*)alloc((size_t)NN * H * 2);
  float* ew      = (float*)alloc((size_t)E_SEE * 4);
  float* csr_ew  = (float*)alloc((size_t)E_SEE * 4);
  int*   csr_src = (int*)alloc((size_t)E_SEE * 4);
  int2*  se      = (int2*)alloc((size_t)E_SEE * 8);
  int*   cnt     = (int*)alloc((size_t)NN * 4);
  int*   off     = (int*)alloc((size_t)(NN + 1) * 4);
  int*   cur     = (int*)alloc((size_t)NN * 4);
  int*   bsum    = (int*)alloc((size_t)NB_SCAN * 4);
  int*   boff    = (int*)alloc((size_t)NB_SCAN * 4);
  float* swsum   = (float*)alloc((size_t)NN * 4);
  float* degf    = (float*)alloc((size_t)NN * 4);
  float* partials= (float*)alloc((size_t)NB_G64 * 256 * 4);
  float* scale1  = (float*)alloc(128 * 4);
  float* shift1  = (float*)alloc(128 * 4);
  float* scale2  = (float*)alloc(128 * 4);
  float* shift2  = (float*)alloc(128 * 4);
  unsigned short* Wqt = (unsigned short*)alloc((size_t)QD * H * 2);
  unsigned short* W1t = (unsigned short*)alloc((size_t)H * H * 2);
  unsigned short* W2t = (unsigned short*)alloc((size_t)H * H * 2);
  float* llmpart = (float*)alloc((size_t)NL * 8 * H * 4);

  hipMemsetAsync(cnt, 0, (size_t)NN * 4, stream);
  hipMemsetAsync(cur, 0, (size_t)NN * 4, stream);

  int ebl = (E_SEE + 255) / 256;
  k_prep<<<320, 256, 0, stream>>>(Wq, W1m, W2m, Wqt, W1t, W2t);
  k_ew_hist<<<ebl, 256, 0, stream>>>(ecs, EI, ewt, Wem, bem, ew, cnt, se);
  k_scan_block<<<NB_SCAN, 256, 0, stream>>>(cnt, bsum);
  k_scan_top<<<1, 512, 0, stream>>>(bsum, boff);
  k_scan_write<<<NB_SCAN, 256, 0, stream>>>(cnt, boff, off);
  k_fill<<<ebl, 256, 0, stream>>>(se, ew, off, cur, csr_src, csr_ew);

  k_llm_part<<<NL * 8, 128, 0, stream>>>(lf, Wl, llmpart);
  k_llm_comb<<<(NL * H + 255) / 256, 256, 0, stream>>>(llmpart, bl, XINI16);
  k_xini<<<NB_X64, 256, 0, stream>>>(qf, Wqt, bq, XINI16);

  int segbl = (NN + 3) / 4;
  // layer 1
  k_seg<false><<<segbl, 256, 0, stream>>>(XINI16, off, csr_src, csr_ew,
                                          nullptr, nullptr, S16, swsum, degf);
  k_gemm<false><<<NB_G64, 256, 0, stream>>>(S16, XINI16, X16, W1t, b1m, b1e, W1e,
                                            nullptr, nullptr, swsum, degf, partials);
  k_bnstats<<<H, 256, 0, stream>>>(partials, g1, beta1, scale1, shift1);
  // layer 2 (BN1+lrelu folded into gather & residual)
  k_seg<true><<<segbl, 256, 0, stream>>>(X16, off, csr_src, csr_ew,
                                         scale1, shift1, S16, swsum, degf);
  k_gemm<true><<<NB_G64, 256, 0, stream>>>(S16, X16, X16, W2t, b2m, b2e, W2e,
                                           scale1, shift1, swsum, degf, partials);
  k_bnstats<<<H, 256, 0, stream>>>(partials, g2, beta2, scale2, shift2);
  // predict (BN2 folded in)
  int pbl = (E_PRED + 3) / 4;
  k_pred<<<pbl, 256, 0, stream>>>(emask, EI, XINI16, X16, scale2, shift2, out);
}